// Round 4
// baseline (116102.661 us; speedup 1.0000x reference)
//
#include <hip/hip_runtime.h>
#include <hip/hip_bf16.h>

// Problem constants
#define BB 32
#define TT 512
#define NN 1024
#define RR 4
#define II 8
#define DT_C 0.1f

// persistent kernel geometry
#define BPB 32                 // blocks per batch
#define GRID (BB * BPB)        // 1024 blocks, 4/CU

// fallback (round-3) tiling
#define NBLK 32
#define ROWS (NN / NBLK)
#define VBLK 16

typedef __attribute__((ext_vector_type(8))) unsigned short ushort8v;

__device__ __forceinline__ float bf2f(unsigned short u) {
    union { unsigned int ui; float f; } cv;
    cv.ui = ((unsigned int)u) << 16;
    return cv.f;
}
__device__ __forceinline__ unsigned short f2bf_rne(float x) {
    union { float f; unsigned int ui; } cv; cv.f = x;
    unsigned int u = cv.ui;
    u += 0x7FFFu + ((u >> 16) & 1u);
    return (unsigned short)(u >> 16);
}
__device__ __forceinline__ float wave_reduce(float v) {
    #pragma unroll
    for (int off = 32; off; off >>= 1) v += __shfl_down(v, off, 64);
    return v;
}

// Permuted layout: position o holds column col(o) = l + 64*(8g+e),
// l=(o>>3)&63, g=o>>9, e=o&7. Row i -> position o(i) = (i>>9? wait) :
// o(i) = ((i>>6)>>3)*512 + (i&63)*8 + ((i>>6)&7).

__global__ __launch_bounds__(256) void k_convJ(const float* __restrict__ J,
                                               unsigned short* __restrict__ Jp) {
    const int row = blockIdx.x;
    const int tid = threadIdx.x;
    __shared__ float rowsh[NN];
    const float4* __restrict__ src = (const float4*)(J + (size_t)row * NN);
    float4* dst4 = (float4*)rowsh;
    for (int k = tid; k < NN / 4; k += 256) dst4[k] = src[k];
    __syncthreads();
    const int o0 = tid * 4;
    unsigned short out[4];
    #pragma unroll
    for (int j = 0; j < 4; ++j) {
        const int o = o0 + j;
        const int l = (o >> 3) & 63, g = o >> 9, e = o & 7;
        out[j] = f2bf_rne(rowsh[l + 64 * (8 * g + e)]);
    }
    uint2 w;
    w.x = (unsigned int)out[0] | ((unsigned int)out[1] << 16);
    w.y = (unsigned int)out[2] | ((unsigned int)out[3] << 16);
    *(uint2*)(Jp + (size_t)row * NN + o0) = w;
}

// ---------------- persistent cooperative kernel ----------------

__device__ __forceinline__ void batch_barrier(unsigned* cnt, unsigned* gen) {
    __syncthreads();
    if (threadIdx.x == 0) {
        __threadfence();
        const unsigned g = __hip_atomic_load(gen, __ATOMIC_RELAXED, __HIP_MEMORY_SCOPE_AGENT);
        const unsigned old = __hip_atomic_fetch_add(cnt, 1u, __ATOMIC_ACQ_REL, __HIP_MEMORY_SCOPE_AGENT);
        if (old == BPB - 1) {
            __hip_atomic_store(cnt, 0u, __ATOMIC_RELAXED, __HIP_MEMORY_SCOPE_AGENT);
            __hip_atomic_fetch_add(gen, 1u, __ATOMIC_RELEASE, __HIP_MEMORY_SCOPE_AGENT);
        } else {
            while (__hip_atomic_load(gen, __ATOMIC_ACQUIRE, __HIP_MEMORY_SCOPE_AGENT) == g)
                __builtin_amdgcn_s_sleep(1);
        }
        __threadfence();
    }
    __syncthreads();
}

__global__ __launch_bounds__(256, 4) void k_persist(
    const unsigned short* __restrict__ Jp,   // [b][row][o] permuted bf16
    unsigned short* __restrict__ V1,         // [b][s][o]   permuted bf16 columns
    unsigned short* __restrict__ V2,         // [b][i][s]   row-major bf16
    float* __restrict__ x, float* __restrict__ nmat,
    float* __restrict__ abuf,                // [b][TT]
    float* __restrict__ zbuf,                // [b][RR]
    float* __restrict__ part,                // [b][40] (0..31 negsum, 32 = 0.1|r|^2)
    unsigned* __restrict__ cnt, unsigned* __restrict__ gen,
    const float* __restrict__ m, const float* __restrict__ wIn,
    const float* __restrict__ inputs, const float* __restrict__ f,
    float* __restrict__ outx, float* __restrict__ outz)
{
    const int bid = blockIdx.x;
    const int b = (bid & 7) * 4 + (bid >> 8);   // batch: 32 blocks share an XCD
    const int k = (bid >> 3) & 31;              // block index within batch
    const int tid = threadIdx.x, lane = tid & 63, wave = tid >> 6;

    __shared__ float r_sh[NN];
    __shared__ float a_sh[TT];
    __shared__ float Jr_sh[32];
    __shared__ float red_neg[4], red_rr[4];
    __shared__ float zsh[RR], esh[RR], ush[II], csh[2];

    const int row_loc = tid >> 3;   // 0..31
    const int sub     = tid & 7;    // 0..7
    const int i_loc   = k * 32 + row_loc;

    unsigned* mycnt = cnt + b;
    unsigned* mygen = gen + b;

    for (int t = 0; t < TT; ++t) {
        // ================= phase A =================
        for (int j = tid; j < NN; j += 256) r_sh[j] = tanhf(x[b * NN + j]);
        __syncthreads();

        // J rows owned by this block
        for (int rr = wave; rr < 32; rr += 4) {
            const int row = k * 32 + rr;
            const ushort8v* __restrict__ Jrow =
                (const ushort8v*)(Jp + ((size_t)b * NN + row) * NN);
            const ushort8v j0 = Jrow[lane];
            const ushort8v j1 = Jrow[64 + lane];
            float acc = 0.0f;
            #pragma unroll
            for (int e = 0; e < 8; ++e)
                acc = fmaf(bf2f(j0[e]), r_sh[lane + 64 * e], acc);
            #pragma unroll
            for (int e = 0; e < 8; ++e)
                acc = fmaf(bf2f(j1[e]), r_sh[lane + 512 + 64 * e], acc);
            acc = wave_reduce(acc);
            if (lane == 0) Jr_sh[rr] = acc;
        }

        // a_s = v_s . r  for s = k + 32*(wave + 4j)
        float negsum = 0.0f;
        for (int s = k + 32 * wave; s < t; s += 128) {
            const ushort8v* __restrict__ col =
                (const ushort8v*)(V1 + ((size_t)b * TT + s) * NN);
            const ushort8v v0 = col[lane];
            const ushort8v v1 = col[64 + lane];
            float acc = 0.0f;
            #pragma unroll
            for (int e = 0; e < 8; ++e)
                acc = fmaf(bf2f(v0[e]), r_sh[lane + 64 * e], acc);
            #pragma unroll
            for (int e = 0; e < 8; ++e)
                acc = fmaf(bf2f(v1[e]), r_sh[lane + 512 + 64 * e], acc);
            acc = wave_reduce(acc);
            if (lane == 0) {
                abuf[b * TT + s] = acc;
                negsum = fmaf(-acc, acc, negsum);
            }
        }
        if (lane == 0) red_neg[wave] = negsum;

        if (k == 0) {   // 0.1 |r|^2
            float p = 0.0f;
            for (int j = tid; j < NN; j += 256) p = fmaf(r_sh[j], r_sh[j], p);
            p = wave_reduce(p);
            if (lane == 0) red_rr[wave] = p;
        }
        if (k == 1 && wave < RR) {   // z = n^T r
            float acc = 0.0f;
            for (int i2 = lane; i2 < NN; i2 += 64)
                acc = fmaf(nmat[((size_t)b * NN + i2) * RR + wave], r_sh[i2], acc);
            acc = wave_reduce(acc);
            if (lane == 0) zbuf[b * RR + wave] = acc;
        }
        __syncthreads();
        if (tid == 0) {
            part[b * 40 + k] = red_neg[0] + red_neg[1] + red_neg[2] + red_neg[3];
            if (k == 0)
                part[b * 40 + 32] = 0.1f * (red_rr[0] + red_rr[1] + red_rr[2] + red_rr[3]);
        }

        batch_barrier(mycnt, mygen);

        // ================= phase B =================
        for (int s = tid; s < t; s += 256) a_sh[s] = abuf[b * TT + s];
        if (tid == 0) {
            float sg = 0.0f;
            #pragma unroll
            for (int q = 0; q <= 32; ++q) sg += part[b * 40 + q];
            const float c = 1.0f / (1.0f + sg);
            csh[0] = c; csh[1] = sqrtf(c);
        }
        if (tid < RR) {
            const float zv = zbuf[b * RR + tid];
            zsh[tid] = zv;
            esh[tid] = zv - f[((size_t)b * TT + t) * RR + tid];
        }
        if (tid >= 64 && tid < 64 + II)
            ush[tid - 64] = inputs[((size_t)b * TT + t) * II + (tid - 64)];
        __syncthreads();

        // Pr_i = 0.1 r_i - sum_s V2[i][s] a_s   (8 threads per row)
        const unsigned short* __restrict__ vrow = V2 + ((size_t)b * NN + i_loc) * TT;
        const int ch8 = (t + 63) >> 6;          // ushort8 vectors per thread
        float acc = 0.0f;
        int s0 = sub * ch8 * 8;
        for (int jv = 0; jv < ch8; ++jv, s0 += 8) {
            if (s0 + 8 <= t) {
                const ushort8v vv = *(const ushort8v*)(vrow + s0);
                #pragma unroll
                for (int e = 0; e < 8; ++e)
                    acc = fmaf(bf2f(vv[e]), a_sh[s0 + e], acc);
            } else {
                for (int e = 0; e < 8; ++e)
                    if (s0 + e < t) acc = fmaf(bf2f(vrow[s0 + e]), a_sh[s0 + e], acc);
            }
        }
        acc += __shfl_down(acc, 4, 8);
        acc += __shfl_down(acc, 2, 8);
        acc += __shfl_down(acc, 1, 8);

        if (sub == 0) {
            const float c = csh[0], sq = csh[1];
            const float pr = 0.1f * r_sh[i_loc] - acc;
            const unsigned short hv = f2bf_rne(sq * pr);
            const int ge = i_loc >> 6;
            const int o = (ge >> 3) * 512 + (i_loc & 63) * 8 + (ge & 7);
            V1[((size_t)b * TT + t) * NN + o] = hv;
            V2[((size_t)b * NN + i_loc) * TT + t] = hv;

            float accx = Jr_sh[row_loc];
            const float4 mv = *(const float4*)(m + ((size_t)b * NN + i_loc) * RR);
            accx = fmaf(mv.x, zsh[0], accx); accx = fmaf(mv.y, zsh[1], accx);
            accx = fmaf(mv.z, zsh[2], accx); accx = fmaf(mv.w, zsh[3], accx);
            const float4* __restrict__ wp = (const float4*)(wIn + ((size_t)b * NN + i_loc) * II);
            const float4 w0 = wp[0], w1 = wp[1];
            accx = fmaf(w0.x, ush[0], accx); accx = fmaf(w0.y, ush[1], accx);
            accx = fmaf(w0.z, ush[2], accx); accx = fmaf(w0.w, ush[3], accx);
            accx = fmaf(w1.x, ush[4], accx); accx = fmaf(w1.y, ush[5], accx);
            accx = fmaf(w1.z, ush[6], accx); accx = fmaf(w1.w, ush[7], accx);
            const float xo = x[b * NN + i_loc];
            const float xn = (1.0f - DT_C) * xo + DT_C * accx;
            x[b * NN + i_loc] = xn;
            outx[((size_t)b * TT + t) * NN + i_loc] = xn;

            float4* __restrict__ np = (float4*)(nmat + ((size_t)b * NN + i_loc) * RR);
            float4 nv = *np;
            const float cpr = c * pr;
            nv.x = fmaf(-cpr, esh[0], nv.x); nv.y = fmaf(-cpr, esh[1], nv.y);
            nv.z = fmaf(-cpr, esh[2], nv.z); nv.w = fmaf(-cpr, esh[3], nv.w);
            *np = nv;
        }
        if (k == 0 && tid < RR) outz[((size_t)b * TT + t) * RR + tid] = zsh[tid];

        batch_barrier(mycnt, mygen);
    }
}

// ---------------- fallback: round-3 two-kernel loop ----------------

__global__ __launch_bounds__(256) void kA_fb(
    const float* __restrict__ x, const unsigned short* __restrict__ Jp,
    const unsigned short* __restrict__ Vp, const float* __restrict__ nmat,
    float* __restrict__ r_out, float* __restrict__ a_out,
    float* __restrict__ Jr, float* __restrict__ zbuf,
    float* __restrict__ part, int t)
{
    const int b   = blockIdx.x / (NBLK + VBLK);
    const int blk = blockIdx.x % (NBLK + VBLK);
    const int tid = threadIdx.x, lane = tid & 63, wave = tid >> 6;

    __shared__ float r_sh[NN];
    __shared__ float red_sh[4];

    for (int j = tid; j < NN; j += 256) {
        const float rv = tanhf(x[b * NN + j]);
        r_sh[j] = rv;
        if (blk == 0) r_out[b * NN + j] = rv;
    }
    __syncthreads();

    if (blk < NBLK) {
        for (int rr = wave; rr < ROWS; rr += 4) {
            const int row = blk * ROWS + rr;
            const ushort8v* __restrict__ Jrow =
                (const ushort8v*)(Jp + ((size_t)b * NN + row) * NN);
            const ushort8v jv0 = Jrow[lane];
            const ushort8v jv1 = Jrow[64 + lane];
            float acc = 0.0f;
            #pragma unroll
            for (int e = 0; e < 8; ++e) acc = fmaf(bf2f(jv0[e]), r_sh[lane + 64 * e], acc);
            #pragma unroll
            for (int e = 0; e < 8; ++e) acc = fmaf(bf2f(jv1[e]), r_sh[lane + 512 + 64 * e], acc);
            acc = wave_reduce(acc);
            if (lane == 0) Jr[b * NN + row] = acc;
        }
        if (blk == 0) {
            float p = 0.0f;
            for (int j = tid; j < NN; j += 256) p = fmaf(r_sh[j], r_sh[j], p);
            p = wave_reduce(p);
            if (lane == 0) red_sh[wave] = p;
            __syncthreads();
            if (tid == 0)
                part[b * 72 + 64] = 0.1f * (red_sh[0] + red_sh[1] + red_sh[2] + red_sh[3]);
            if (wave < RR) {
                float acc = 0.0f;
                for (int i2 = lane; i2 < NN; i2 += 64)
                    acc = fmaf(nmat[((size_t)b * NN + i2) * RR + wave], r_sh[i2], acc);
                acc = wave_reduce(acc);
                if (lane == 0) zbuf[b * RR + wave] = acc;
            }
        }
    } else {
        const int wid = (blk - NBLK) * 4 + wave;
        float negsum = 0.0f;
        for (int s = wid; s < t; s += 64) {
            const ushort8v* __restrict__ col =
                (const ushort8v*)(Vp + ((size_t)b * TT + s) * NN);
            const ushort8v vv0 = col[lane];
            const ushort8v vv1 = col[64 + lane];
            float acc = 0.0f;
            #pragma unroll
            for (int e = 0; e < 8; ++e) acc = fmaf(bf2f(vv0[e]), r_sh[lane + 64 * e], acc);
            #pragma unroll
            for (int e = 0; e < 8; ++e) acc = fmaf(bf2f(vv1[e]), r_sh[lane + 512 + 64 * e], acc);
            acc = wave_reduce(acc);
            if (lane == 0) {
                a_out[b * TT + s] = acc;
                negsum = fmaf(-acc, acc, negsum);
            }
        }
        if (lane == 0) part[b * 72 + wid] = negsum;
    }
}

__global__ __launch_bounds__(256) void kB_fb(
    unsigned short* __restrict__ Vp, const float* __restrict__ r,
    const float* __restrict__ a, const float* __restrict__ Jr,
    const float* __restrict__ zbuf, const float* __restrict__ part,
    float* __restrict__ x, float* __restrict__ nmat,
    const float* __restrict__ m, const float* __restrict__ wIn,
    const float* __restrict__ inputs, const float* __restrict__ f,
    float* __restrict__ outx, float* __restrict__ outz, int t)
{
    const int b   = blockIdx.x >> 3;
    const int tb  = blockIdx.x & 7;
    const int tid = threadIdx.x;
    const int pl    = tid & 63;
    const int slice = tid >> 6;

    __shared__ float a_sh[TT];
    __shared__ float ps[4][128];
    __shared__ float zsh[RR], esh[RR], ush[II];

    for (int s = tid; s < t; s += 256) a_sh[s] = a[b * TT + s];
    if (tid < RR) {
        const float zv = zbuf[b * RR + tid];
        zsh[tid] = zv;
        esh[tid] = zv - f[((size_t)b * TT + t) * RR + tid];
    }
    if (tid >= 64 && tid < 64 + II)
        ush[tid - 64] = inputs[((size_t)b * TT + t) * II + (tid - 64)];
    __syncthreads();

    const int p0 = (tb * 64 + pl) * 2;
    const unsigned short* __restrict__ Vb = Vp + (size_t)b * TT * NN;

    const int s_begin = (t * slice) >> 2;
    const int s_end   = (t * (slice + 1)) >> 2;
    float acc0 = 0.0f, acc1 = 0.0f;
    #pragma unroll 4
    for (int s = s_begin; s < s_end; ++s) {
        const unsigned int w = *(const unsigned int*)(Vb + (size_t)s * NN + p0);
        const float av = a_sh[s];
        acc0 = fmaf(bf2f((unsigned short)(w & 0xFFFFu)), av, acc0);
        acc1 = fmaf(bf2f((unsigned short)(w >> 16)), av, acc1);
    }
    ps[slice][pl * 2]     = acc0;
    ps[slice][pl * 2 + 1] = acc1;
    __syncthreads();

    if (slice == 0) {
        const int l = (p0 >> 3) & 63, g = p0 >> 9, e = p0 & 7;
        const int i0 = l + 64 * (8 * g + e);
        const int i1 = i0 + 64;
        const float s0 = ps[0][pl * 2] + ps[1][pl * 2] + ps[2][pl * 2] + ps[3][pl * 2];
        const float s1 = ps[0][pl * 2 + 1] + ps[1][pl * 2 + 1] + ps[2][pl * 2 + 1] + ps[3][pl * 2 + 1];

        float sg = 0.0f;
        #pragma unroll
        for (int q = 0; q < 65; ++q) sg += part[b * 72 + q];
        const float c  = 1.0f / (1.0f + sg);
        const float sq = sqrtf(c);

        const float pr0 = 0.1f * r[b * NN + i0] - s0;
        const float pr1 = 0.1f * r[b * NN + i1] - s1;

        unsigned int wv = (unsigned int)f2bf_rne(sq * pr0) |
                          ((unsigned int)f2bf_rne(sq * pr1) << 16);
        *(unsigned int*)(Vp + ((size_t)b * TT + t) * NN + p0) = wv;

        #pragma unroll
        for (int which = 0; which < 2; ++which) {
            const int   i  = which ? i1 : i0;
            const float pr = which ? pr1 : pr0;
            float acc = Jr[b * NN + i];
            const float4 mv = *(const float4*)(m + ((size_t)b * NN + i) * RR);
            acc = fmaf(mv.x, zsh[0], acc); acc = fmaf(mv.y, zsh[1], acc);
            acc = fmaf(mv.z, zsh[2], acc); acc = fmaf(mv.w, zsh[3], acc);
            const float4* __restrict__ wp = (const float4*)(wIn + ((size_t)b * NN + i) * II);
            const float4 w0 = wp[0], w1 = wp[1];
            acc = fmaf(w0.x, ush[0], acc); acc = fmaf(w0.y, ush[1], acc);
            acc = fmaf(w0.z, ush[2], acc); acc = fmaf(w0.w, ush[3], acc);
            acc = fmaf(w1.x, ush[4], acc); acc = fmaf(w1.y, ush[5], acc);
            acc = fmaf(w1.z, ush[6], acc); acc = fmaf(w1.w, ush[7], acc);
            const float xo = x[b * NN + i];
            const float xn = (1.0f - DT_C) * xo + DT_C * acc;
            x[b * NN + i] = xn;
            outx[((size_t)b * TT + t) * NN + i] = xn;

            float4* __restrict__ np = (float4*)(nmat + ((size_t)b * NN + i) * RR);
            float4 nv = *np;
            const float cpr = c * pr;
            nv.x = fmaf(-cpr, esh[0], nv.x); nv.y = fmaf(-cpr, esh[1], nv.y);
            nv.z = fmaf(-cpr, esh[2], nv.z); nv.w = fmaf(-cpr, esh[3], nv.w);
            *np = nv;
        }
    }
    if (tb == 0 && tid < RR) outz[((size_t)b * TT + t) * RR + tid] = zsh[tid];
}

extern "C" void kernel_launch(void* const* d_in, const int* in_sizes, int n_in,
                              void* d_out, int out_size, void* d_ws, size_t ws_size,
                              hipStream_t stream) {
    const float* inputs = (const float*)d_in[0];   // (B,T,I,1)
    const float* f      = (const float*)d_in[1];   // (B,T,R,1)
    const float* J      = (const float*)d_in[2];   // (B,N,N)
    const float* wIn    = (const float*)d_in[3];   // (B,N,I)
    const float* m      = (const float*)d_in[4];   // (B,N,R)

    float* outx = (float*)d_out;                   // (B,T,N)
    float* outz = outx + (size_t)BB * TT * NN;     // (B,T,R)

    char* ws = (char*)d_ws;
    size_t off = 0;
    unsigned short* Jp = (unsigned short*)(ws + off); off += (size_t)BB * NN * NN * 2;
    unsigned short* V1 = (unsigned short*)(ws + off); off += (size_t)BB * TT * NN * 2;
    unsigned short* V2 = (unsigned short*)(ws + off); off += (size_t)BB * NN * TT * 2;
    float* x      = (float*)(ws + off); off += (size_t)BB * NN * 4;
    float* nm     = (float*)(ws + off); off += (size_t)BB * NN * RR * 4;
    float* abuf   = (float*)(ws + off); off += (size_t)BB * TT * 4;
    float* zb     = (float*)(ws + off); off += (size_t)BB * RR * 4;
    float* part   = (float*)(ws + off); off += (size_t)BB * 40 * 4;
    unsigned* cnt = (unsigned*)(ws + off); off += (size_t)BB * 4;
    unsigned* gen = (unsigned*)(ws + off); off += (size_t)BB * 4;
    float* rbuf   = (float*)(ws + off); off += (size_t)BB * NN * 4;   // fallback
    float* Jrb    = (float*)(ws + off); off += (size_t)BB * NN * 4;   // fallback
    float* part72 = (float*)(ws + off); off += (size_t)BB * 72 * 4;   // fallback

    hipMemsetAsync(x,   0, (size_t)BB * NN * sizeof(float), stream);
    hipMemsetAsync(nm,  0, (size_t)BB * NN * RR * sizeof(float), stream);
    hipMemsetAsync(cnt, 0, (size_t)BB * sizeof(unsigned), stream);
    hipMemsetAsync(gen, 0, (size_t)BB * sizeof(unsigned), stream);

    k_convJ<<<BB * NN, 256, 0, stream>>>(J, Jp);

    void* kargs[] = {
        (void*)&Jp, (void*)&V1, (void*)&V2, (void*)&x, (void*)&nm,
        (void*)&abuf, (void*)&zb, (void*)&part, (void*)&cnt, (void*)&gen,
        (void*)&m, (void*)&wIn, (void*)&inputs, (void*)&f,
        (void*)&outx, (void*)&outz
    };
    hipError_t rc = hipLaunchCooperativeKernel((const void*)k_persist,
                                               dim3(GRID), dim3(256),
                                               kargs, 0, stream);
    if (rc != hipSuccess) {
        // fallback: proven round-3 path
        for (int t = 0; t < TT; ++t) {
            kA_fb<<<BB * (NBLK + VBLK), 256, 0, stream>>>(x, Jp, V1, nm, rbuf, abuf,
                                                          Jrb, zb, part72, t);
            kB_fb<<<BB * 8, 256, 0, stream>>>(V1, rbuf, abuf, Jrb, zb, part72,
                                              x, nm, m, wIn, inputs, f, outx, outz, t);
        }
    }
}

// Round 5
// 9451.477 us; speedup vs baseline: 12.2841x; 12.2841x over previous
//
#include <hip/hip_runtime.h>
#include <hip/hip_bf16.h>

// Problem constants
#define BB 32
#define TT 512
#define NN 1024
#define RR 4
#define II 8
#define DT_C 0.1f

// persistent kernel geometry
#define BPB 32                 // blocks per batch
#define GRID (BB * BPB)        // 1024 blocks, 4/CU

// fallback (round-3) tiling
#define NBLK 32
#define ROWS (NN / NBLK)
#define VBLK 16

typedef __attribute__((ext_vector_type(8))) unsigned short ushort8v;

__device__ __forceinline__ float bf2f(unsigned short u) {
    union { unsigned int ui; float f; } cv;
    cv.ui = ((unsigned int)u) << 16;
    return cv.f;
}
__device__ __forceinline__ unsigned short f2bf_rne(float x) {
    union { float f; unsigned int ui; } cv; cv.f = x;
    unsigned int u = cv.ui;
    u += 0x7FFFu + ((u >> 16) & 1u);
    return (unsigned short)(u >> 16);
}
__device__ __forceinline__ float wave_reduce(float v) {
    #pragma unroll
    for (int off = 32; off; off >>= 1) v += __shfl_down(v, off, 64);
    return v;
}

// ---- LLC-direct (bypass L1/L2, no cache maintenance) access helpers ----
__device__ __forceinline__ void llc_ld16x2(const void* p0, const void* p1,
                                           uint4& a, uint4& b) {
    asm volatile("global_load_dwordx4 %0, %2, off sc0 sc1\n\t"
                 "global_load_dwordx4 %1, %3, off sc0 sc1\n\t"
                 "s_waitcnt vmcnt(0)"
                 : "=&v"(a), "=&v"(b) : "v"(p0), "v"(p1) : "memory");
}
__device__ __forceinline__ uint4 llc_ld16(const void* p) {
    uint4 r;
    asm volatile("global_load_dwordx4 %0, %1, off sc0 sc1\n\ts_waitcnt vmcnt(0)"
                 : "=&v"(r) : "v"(p) : "memory");
    return r;
}
__device__ __forceinline__ float llc_ldf(const float* p) {
    float r;
    asm volatile("global_load_dword %0, %1, off sc0 sc1\n\ts_waitcnt vmcnt(0)"
                 : "=&v"(r) : "v"(p) : "memory");
    return r;
}
__device__ __forceinline__ void llc_ld4f(const float* p0, const float* p1,
                                         const float* p2, const float* p3,
                                         float& a, float& b, float& c, float& d) {
    asm volatile("global_load_dword %0, %4, off sc0 sc1\n\t"
                 "global_load_dword %1, %5, off sc0 sc1\n\t"
                 "global_load_dword %2, %6, off sc0 sc1\n\t"
                 "global_load_dword %3, %7, off sc0 sc1\n\t"
                 "s_waitcnt vmcnt(0)"
                 : "=&v"(a), "=&v"(b), "=&v"(c), "=&v"(d)
                 : "v"(p0), "v"(p1), "v"(p2), "v"(p3) : "memory");
}
__device__ __forceinline__ void llc_stf(float* p, float v) {
    asm volatile("global_store_dword %0, %1, off sc0 sc1" :: "v"(p), "v"(v) : "memory");
}
__device__ __forceinline__ void llc_st16b(unsigned short* p, unsigned short v) {
    asm volatile("global_store_short %0, %1, off sc0 sc1"
                 :: "v"(p), "v"((unsigned)v) : "memory");
}

__device__ __forceinline__ void accum8(float& acc, const uint4 q, const float* ap) {
    acc = fmaf(bf2f((unsigned short)(q.x & 0xffffu)), ap[0], acc);
    acc = fmaf(bf2f((unsigned short)(q.x >> 16)),     ap[1], acc);
    acc = fmaf(bf2f((unsigned short)(q.y & 0xffffu)), ap[2], acc);
    acc = fmaf(bf2f((unsigned short)(q.y >> 16)),     ap[3], acc);
    acc = fmaf(bf2f((unsigned short)(q.z & 0xffffu)), ap[4], acc);
    acc = fmaf(bf2f((unsigned short)(q.z >> 16)),     ap[5], acc);
    acc = fmaf(bf2f((unsigned short)(q.w & 0xffffu)), ap[6], acc);
    acc = fmaf(bf2f((unsigned short)(q.w >> 16)),     ap[7], acc);
}

// Permuted layout: position o holds column col(o) = l + 64*(8g+e),
// l=(o>>3)&63, g=o>>9, e=o&7.

__global__ __launch_bounds__(256) void k_convJ(const float* __restrict__ J,
                                               unsigned short* __restrict__ Jp) {
    const int row = blockIdx.x;
    const int tid = threadIdx.x;
    __shared__ float rowsh[NN];
    const float4* __restrict__ src = (const float4*)(J + (size_t)row * NN);
    float4* dst4 = (float4*)rowsh;
    for (int k = tid; k < NN / 4; k += 256) dst4[k] = src[k];
    __syncthreads();
    const int o0 = tid * 4;
    unsigned short out[4];
    #pragma unroll
    for (int j = 0; j < 4; ++j) {
        const int o = o0 + j;
        const int l = (o >> 3) & 63, g = o >> 9, e = o & 7;
        out[j] = f2bf_rne(rowsh[l + 64 * (8 * g + e)]);
    }
    uint2 w;
    w.x = (unsigned int)out[0] | ((unsigned int)out[1] << 16);
    w.y = (unsigned int)out[2] | ((unsigned int)out[3] << 16);
    *(uint2*)(Jp + (size_t)row * NN + o0) = w;
}

// ---------------- persistent cooperative kernel ----------------
// Monotonic-epoch barrier, RELAXED atomics only (no wbl2/inv storms).
__device__ __forceinline__ void batch_barrier(unsigned* cnt, unsigned* gen,
                                              unsigned expect) {
    asm volatile("s_waitcnt vmcnt(0) lgkmcnt(0)" ::: "memory");
    __syncthreads();
    if (threadIdx.x == 0) {
        unsigned old = __hip_atomic_fetch_add(cnt, 1u, __ATOMIC_RELAXED,
                                              __HIP_MEMORY_SCOPE_AGENT);
        if (old == BPB - 1u) {
            __hip_atomic_store(cnt, 0u, __ATOMIC_RELAXED, __HIP_MEMORY_SCOPE_AGENT);
            asm volatile("s_waitcnt vmcnt(0)" ::: "memory");
            __hip_atomic_fetch_add(gen, 1u, __ATOMIC_RELAXED, __HIP_MEMORY_SCOPE_AGENT);
        } else {
            while (__hip_atomic_load(gen, __ATOMIC_RELAXED, __HIP_MEMORY_SCOPE_AGENT)
                   < expect)
                __builtin_amdgcn_s_sleep(2);
        }
    }
    __syncthreads();
}

#define ACC2(q, base) \
    acc = fmaf(bf2f((unsigned short)((q) & 0xffffu)), r_sh[(base)], acc); \
    acc = fmaf(bf2f((unsigned short)((q) >> 16)), r_sh[(base) + 64], acc);

__global__ __launch_bounds__(256, 4) void k_persist(
    const unsigned short* __restrict__ Jp,   // [b][row][o] permuted bf16 (cached path)
    unsigned short* __restrict__ V1,         // [b][s][o]   columns (LLC-direct)
    unsigned short* __restrict__ V2,         // [b][i][s]   rows    (LLC-direct)
    float* __restrict__ x,                   // LLC-direct
    float* __restrict__ abuf,                // [b][TT] LLC-direct
    float* __restrict__ part,                // [b][64]: 0..31 negsum, 32 = 0.1|r|^2
    float* __restrict__ part2,               // [b][128]: z partials (k*4+q)
    unsigned* __restrict__ cnt, unsigned* __restrict__ gen,
    const float* __restrict__ m, const float* __restrict__ wIn,
    const float* __restrict__ inputs, const float* __restrict__ f,
    float* __restrict__ outx, float* __restrict__ outz)
{
    const int bid = blockIdx.x;
    const int b = (bid & 7) * 4 + (bid >> 8);   // batch: 32 blocks share an XCD (perf only)
    const int k = (bid >> 3) & 31;              // block index within batch
    const int tid = threadIdx.x, lane = tid & 63, wave = tid >> 6;
    const int row_loc = tid >> 3, sub = tid & 7;
    const int i_loc = k * 32 + row_loc;

    __shared__ float r_sh[NN];
    __shared__ float a_sh[TT];
    __shared__ float Jr_sh[32];
    __shared__ float zred[32][4];
    __shared__ float red_neg[4], red_rr[4];
    __shared__ float sgred[33];
    __shared__ float zr2[128];
    __shared__ float zsh[RR], esh[RR], ush[II], csh[2];

    unsigned* mycnt = cnt + b * 32;   // 128B per batch: no false sharing
    unsigned* mygen = gen + b * 32;
    unsigned bar = 0;

    float4 nrow = {0.f, 0.f, 0.f, 0.f};   // this row's n (owner: sub==0)
    float xreg = 0.f;                      // this row's x (owner: sub==0)

    for (int t = 0; t < TT; ++t) {
        // ================= phase A =================
        {
            float x0, x1, x2, x3;
            const float* xb = x + b * NN + tid;
            llc_ld4f(xb, xb + 256, xb + 512, xb + 768, x0, x1, x2, x3);
            r_sh[tid]       = tanhf(x0);
            r_sh[tid + 256] = tanhf(x1);
            r_sh[tid + 512] = tanhf(x2);
            r_sh[tid + 768] = tanhf(x3);
        }
        __syncthreads();

        // Jr for this block's rows (normal cached loads: J stays hot in L2/LLC)
        for (int rr = wave; rr < 32; rr += 4) {
            const int row = k * 32 + rr;
            const ushort8v* __restrict__ Jrow =
                (const ushort8v*)(Jp + ((size_t)b * NN + row) * NN);
            const ushort8v j0 = Jrow[lane];
            const ushort8v j1 = Jrow[64 + lane];
            float acc = 0.f;
            #pragma unroll
            for (int e = 0; e < 8; ++e)
                acc = fmaf(bf2f(j0[e]), r_sh[lane + 64 * e], acc);
            #pragma unroll
            for (int e = 0; e < 8; ++e)
                acc = fmaf(bf2f(j1[e]), r_sh[lane + 512 + 64 * e], acc);
            acc = wave_reduce(acc);
            if (lane == 0) Jr_sh[rr] = acc;
        }

        // z partials from register-resident n
        if (sub == 0) {
            const float rv = r_sh[i_loc];
            zred[row_loc][0] = nrow.x * rv;
            zred[row_loc][1] = nrow.y * rv;
            zred[row_loc][2] = nrow.z * rv;
            zred[row_loc][3] = nrow.w * rv;
        }

        // a_s = v_s . r  for s = k + 32*wave + 128j  (LLC-direct loads)
        float negsum = 0.f;
        for (int s = k + 32 * wave; s < t; s += 128) {
            const unsigned short* colp = V1 + ((size_t)b * TT + s) * NN;
            uint4 q0, q1;
            llc_ld16x2(colp + lane * 8, colp + (64 + lane) * 8, q0, q1);
            float acc = 0.f;
            ACC2(q0.x, lane);       ACC2(q0.y, lane + 128);
            ACC2(q0.z, lane + 256); ACC2(q0.w, lane + 384);
            ACC2(q1.x, lane + 512); ACC2(q1.y, lane + 640);
            ACC2(q1.z, lane + 768); ACC2(q1.w, lane + 896);
            acc = wave_reduce(acc);
            if (lane == 0) {
                llc_stf(abuf + b * TT + s, acc);
                negsum = fmaf(-acc, acc, negsum);
            }
        }
        if (lane == 0) red_neg[wave] = negsum;

        if (k == 0) {
            float p = 0.f;
            for (int j = tid; j < NN; j += 256) p = fmaf(r_sh[j], r_sh[j], p);
            p = wave_reduce(p);
            if (lane == 0) red_rr[wave] = p;
        }
        __syncthreads();
        if (tid < 4) {
            float zp = 0.f;
            #pragma unroll
            for (int kk = 0; kk < 32; ++kk) zp += zred[kk][tid];
            llc_stf(part2 + b * 128 + k * 4 + tid, zp);
        }
        if (tid == 0)
            llc_stf(part + b * 64 + k,
                    red_neg[0] + red_neg[1] + red_neg[2] + red_neg[3]);
        if (k == 0 && tid == 0)
            llc_stf(part + b * 64 + 32,
                    0.1f * (red_rr[0] + red_rr[1] + red_rr[2] + red_rr[3]));

        batch_barrier(mycnt, mygen, ++bar);

        // ================= phase B =================
        const int nv4 = (t + 3) >> 2;
        if (tid < nv4) {
            union { uint4 u; float4 fv; } cv;
            cv.u = llc_ld16(abuf + b * TT + tid * 4);
            const int s0 = tid * 4;
            a_sh[s0]     = (s0     < t) ? cv.fv.x : 0.f;
            a_sh[s0 + 1] = (s0 + 1 < t) ? cv.fv.y : 0.f;
            a_sh[s0 + 2] = (s0 + 2 < t) ? cv.fv.z : 0.f;
            a_sh[s0 + 3] = (s0 + 3 < t) ? cv.fv.w : 0.f;
        }
        for (int j2 = nv4 * 4 + tid; j2 < TT; j2 += 256) a_sh[j2] = 0.f;
        if (tid < 33) sgred[tid] = llc_ldf(part + b * 64 + tid);
        if (tid >= 64 && tid < 192) zr2[tid - 64] = llc_ldf(part2 + b * 128 + (tid - 64));
        if (tid >= 192 && tid < 192 + II)
            ush[tid - 192] = inputs[((size_t)b * TT + t) * II + (tid - 192)];
        __syncthreads();
        if (tid == 0) {
            float sg = 0.f;
            #pragma unroll
            for (int q2 = 0; q2 < 33; ++q2) sg += sgred[q2];
            const float c = 1.f / (1.f + sg);
            csh[0] = c; csh[1] = sqrtf(c);
        }
        if (tid < 4) {
            float zq = 0.f;
            #pragma unroll
            for (int kk = 0; kk < 32; ++kk) zq += zr2[kk * 4 + tid];
            zsh[tid] = zq;
            esh[tid] = zq - f[((size_t)b * TT + t) * RR + tid];
        }
        __syncthreads();

        // Pr_i = 0.1 r_i - sum_s V2[i][s] a_s  (8 threads/row, interleaved chunks)
        const unsigned short* vrow = V2 + ((size_t)b * NN + i_loc) * TT;
        const int nj = (t + 63) >> 6;
        float acc = 0.f;
        int j2 = 0;
        for (; j2 + 2 <= nj; j2 += 2) {
            uint4 qa, qb;
            const int o0 = j2 * 64 + sub * 8, o1 = o0 + 64;
            llc_ld16x2(vrow + o0, vrow + o1, qa, qb);
            accum8(acc, qa, a_sh + o0);
            accum8(acc, qb, a_sh + o1);
        }
        if (j2 < nj) {
            const int o0 = j2 * 64 + sub * 8;
            uint4 qa = llc_ld16(vrow + o0);
            accum8(acc, qa, a_sh + o0);
        }
        acc += __shfl_down(acc, 4, 8);
        acc += __shfl_down(acc, 2, 8);
        acc += __shfl_down(acc, 1, 8);

        if (sub == 0) {
            const float c = csh[0], sq = csh[1];
            const float pr = 0.1f * r_sh[i_loc] - acc;
            const unsigned short hv = f2bf_rne(sq * pr);
            const int ge = i_loc >> 6;
            const int o = (ge >> 3) * 512 + (i_loc & 63) * 8 + (ge & 7);
            llc_st16b(V1 + ((size_t)b * TT + t) * NN + o, hv);
            llc_st16b(V2 + ((size_t)b * NN + i_loc) * TT + t, hv);

            float accx = Jr_sh[row_loc];
            const float4 mv = *(const float4*)(m + ((size_t)b * NN + i_loc) * RR);
            accx = fmaf(mv.x, zsh[0], accx); accx = fmaf(mv.y, zsh[1], accx);
            accx = fmaf(mv.z, zsh[2], accx); accx = fmaf(mv.w, zsh[3], accx);
            const float4* __restrict__ wp =
                (const float4*)(wIn + ((size_t)b * NN + i_loc) * II);
            const float4 w0 = wp[0], w1 = wp[1];
            accx = fmaf(w0.x, ush[0], accx); accx = fmaf(w0.y, ush[1], accx);
            accx = fmaf(w0.z, ush[2], accx); accx = fmaf(w0.w, ush[3], accx);
            accx = fmaf(w1.x, ush[4], accx); accx = fmaf(w1.y, ush[5], accx);
            accx = fmaf(w1.z, ush[6], accx); accx = fmaf(w1.w, ush[7], accx);
            const float xn = (1.0f - DT_C) * xreg + DT_C * accx;
            xreg = xn;
            llc_stf(x + b * NN + i_loc, xn);
            outx[((size_t)b * TT + t) * NN + i_loc] = xn;

            const float cpr = c * pr;
            nrow.x = fmaf(-cpr, esh[0], nrow.x);
            nrow.y = fmaf(-cpr, esh[1], nrow.y);
            nrow.z = fmaf(-cpr, esh[2], nrow.z);
            nrow.w = fmaf(-cpr, esh[3], nrow.w);
        }
        if (k == 0 && tid < RR) outz[((size_t)b * TT + t) * RR + tid] = zsh[tid];

        batch_barrier(mycnt, mygen, ++bar);
    }
}

// ---------------- fallback: round-3 two-kernel loop ----------------

__global__ __launch_bounds__(256) void kA_fb(
    const float* __restrict__ x, const unsigned short* __restrict__ Jp,
    const unsigned short* __restrict__ Vp, const float* __restrict__ nmat,
    float* __restrict__ r_out, float* __restrict__ a_out,
    float* __restrict__ Jr, float* __restrict__ zbuf,
    float* __restrict__ part, int t)
{
    const int b   = blockIdx.x / (NBLK + VBLK);
    const int blk = blockIdx.x % (NBLK + VBLK);
    const int tid = threadIdx.x, lane = tid & 63, wave = tid >> 6;

    __shared__ float r_sh[NN];
    __shared__ float red_sh[4];

    for (int j = tid; j < NN; j += 256) {
        const float rv = tanhf(x[b * NN + j]);
        r_sh[j] = rv;
        if (blk == 0) r_out[b * NN + j] = rv;
    }
    __syncthreads();

    if (blk < NBLK) {
        for (int rr = wave; rr < ROWS; rr += 4) {
            const int row = blk * ROWS + rr;
            const ushort8v* __restrict__ Jrow =
                (const ushort8v*)(Jp + ((size_t)b * NN + row) * NN);
            const ushort8v jv0 = Jrow[lane];
            const ushort8v jv1 = Jrow[64 + lane];
            float acc = 0.0f;
            #pragma unroll
            for (int e = 0; e < 8; ++e) acc = fmaf(bf2f(jv0[e]), r_sh[lane + 64 * e], acc);
            #pragma unroll
            for (int e = 0; e < 8; ++e) acc = fmaf(bf2f(jv1[e]), r_sh[lane + 512 + 64 * e], acc);
            acc = wave_reduce(acc);
            if (lane == 0) Jr[b * NN + row] = acc;
        }
        if (blk == 0) {
            float p = 0.0f;
            for (int j = tid; j < NN; j += 256) p = fmaf(r_sh[j], r_sh[j], p);
            p = wave_reduce(p);
            if (lane == 0) red_sh[wave] = p;
            __syncthreads();
            if (tid == 0)
                part[b * 72 + 64] = 0.1f * (red_sh[0] + red_sh[1] + red_sh[2] + red_sh[3]);
            if (wave < RR) {
                float acc = 0.0f;
                for (int i2 = lane; i2 < NN; i2 += 64)
                    acc = fmaf(nmat[((size_t)b * NN + i2) * RR + wave], r_sh[i2], acc);
                acc = wave_reduce(acc);
                if (lane == 0) zbuf[b * RR + wave] = acc;
            }
        }
    } else {
        const int wid = (blk - NBLK) * 4 + wave;
        float negsum = 0.0f;
        for (int s = wid; s < t; s += 64) {
            const ushort8v* __restrict__ col =
                (const ushort8v*)(Vp + ((size_t)b * TT + s) * NN);
            const ushort8v vv0 = col[lane];
            const ushort8v vv1 = col[64 + lane];
            float acc = 0.0f;
            #pragma unroll
            for (int e = 0; e < 8; ++e) acc = fmaf(bf2f(vv0[e]), r_sh[lane + 64 * e], acc);
            #pragma unroll
            for (int e = 0; e < 8; ++e) acc = fmaf(bf2f(vv1[e]), r_sh[lane + 512 + 64 * e], acc);
            acc = wave_reduce(acc);
            if (lane == 0) {
                a_out[b * TT + s] = acc;
                negsum = fmaf(-acc, acc, negsum);
            }
        }
        if (lane == 0) part[b * 72 + wid] = negsum;
    }
}

__global__ __launch_bounds__(256) void kB_fb(
    unsigned short* __restrict__ Vp, const float* __restrict__ r,
    const float* __restrict__ a, const float* __restrict__ Jr,
    const float* __restrict__ zbuf, const float* __restrict__ part,
    float* __restrict__ x, float* __restrict__ nmat,
    const float* __restrict__ m, const float* __restrict__ wIn,
    const float* __restrict__ inputs, const float* __restrict__ f,
    float* __restrict__ outx, float* __restrict__ outz, int t)
{
    const int b   = blockIdx.x >> 3;
    const int tb  = blockIdx.x & 7;
    const int tid = threadIdx.x;
    const int pl    = tid & 63;
    const int slice = tid >> 6;

    __shared__ float a_sh[TT];
    __shared__ float ps[4][128];
    __shared__ float zsh[RR], esh[RR], ush[II];

    for (int s = tid; s < t; s += 256) a_sh[s] = a[b * TT + s];
    if (tid < RR) {
        const float zv = zbuf[b * RR + tid];
        zsh[tid] = zv;
        esh[tid] = zv - f[((size_t)b * TT + t) * RR + tid];
    }
    if (tid >= 64 && tid < 64 + II)
        ush[tid - 64] = inputs[((size_t)b * TT + t) * II + (tid - 64)];
    __syncthreads();

    const int p0 = (tb * 64 + pl) * 2;
    const unsigned short* __restrict__ Vb = Vp + (size_t)b * TT * NN;

    const int s_begin = (t * slice) >> 2;
    const int s_end   = (t * (slice + 1)) >> 2;
    float acc0 = 0.0f, acc1 = 0.0f;
    #pragma unroll 4
    for (int s = s_begin; s < s_end; ++s) {
        const unsigned int w = *(const unsigned int*)(Vb + (size_t)s * NN + p0);
        const float av = a_sh[s];
        acc0 = fmaf(bf2f((unsigned short)(w & 0xFFFFu)), av, acc0);
        acc1 = fmaf(bf2f((unsigned short)(w >> 16)), av, acc1);
    }
    ps[slice][pl * 2]     = acc0;
    ps[slice][pl * 2 + 1] = acc1;
    __syncthreads();

    if (slice == 0) {
        const int l = (p0 >> 3) & 63, g = p0 >> 9, e = p0 & 7;
        const int i0 = l + 64 * (8 * g + e);
        const int i1 = i0 + 64;
        const float s0 = ps[0][pl * 2] + ps[1][pl * 2] + ps[2][pl * 2] + ps[3][pl * 2];
        const float s1 = ps[0][pl * 2 + 1] + ps[1][pl * 2 + 1] + ps[2][pl * 2 + 1] + ps[3][pl * 2 + 1];

        float sg = 0.0f;
        #pragma unroll
        for (int q = 0; q < 65; ++q) sg += part[b * 72 + q];
        const float c  = 1.0f / (1.0f + sg);
        const float sq = sqrtf(c);

        const float pr0 = 0.1f * r[b * NN + i0] - s0;
        const float pr1 = 0.1f * r[b * NN + i1] - s1;

        unsigned int wv = (unsigned int)f2bf_rne(sq * pr0) |
                          ((unsigned int)f2bf_rne(sq * pr1) << 16);
        *(unsigned int*)(Vp + ((size_t)b * TT + t) * NN + p0) = wv;

        #pragma unroll
        for (int which = 0; which < 2; ++which) {
            const int   i  = which ? i1 : i0;
            const float pr = which ? pr1 : pr0;
            float acc = Jr[b * NN + i];
            const float4 mv = *(const float4*)(m + ((size_t)b * NN + i) * RR);
            acc = fmaf(mv.x, zsh[0], acc); acc = fmaf(mv.y, zsh[1], acc);
            acc = fmaf(mv.z, zsh[2], acc); acc = fmaf(mv.w, zsh[3], acc);
            const float4* __restrict__ wp = (const float4*)(wIn + ((size_t)b * NN + i) * II);
            const float4 w0 = wp[0], w1 = wp[1];
            acc = fmaf(w0.x, ush[0], acc); acc = fmaf(w0.y, ush[1], acc);
            acc = fmaf(w0.z, ush[2], acc); acc = fmaf(w0.w, ush[3], acc);
            acc = fmaf(w1.x, ush[4], acc); acc = fmaf(w1.y, ush[5], acc);
            acc = fmaf(w1.z, ush[6], acc); acc = fmaf(w1.w, ush[7], acc);
            const float xo = x[b * NN + i];
            const float xn = (1.0f - DT_C) * xo + DT_C * acc;
            x[b * NN + i] = xn;
            outx[((size_t)b * TT + t) * NN + i] = xn;

            float4* __restrict__ np = (float4*)(nmat + ((size_t)b * NN + i) * RR);
            float4 nv = *np;
            const float cpr = c * pr;
            nv.x = fmaf(-cpr, esh[0], nv.x); nv.y = fmaf(-cpr, esh[1], nv.y);
            nv.z = fmaf(-cpr, esh[2], nv.z); nv.w = fmaf(-cpr, esh[3], nv.w);
            *np = nv;
        }
    }
    if (tb == 0 && tid < RR) outz[((size_t)b * TT + t) * RR + tid] = zsh[tid];
}

extern "C" void kernel_launch(void* const* d_in, const int* in_sizes, int n_in,
                              void* d_out, int out_size, void* d_ws, size_t ws_size,
                              hipStream_t stream) {
    const float* inputs = (const float*)d_in[0];   // (B,T,I,1)
    const float* f      = (const float*)d_in[1];   // (B,T,R,1)
    const float* J      = (const float*)d_in[2];   // (B,N,N)
    const float* wIn    = (const float*)d_in[3];   // (B,N,I)
    const float* m      = (const float*)d_in[4];   // (B,N,R)

    float* outx = (float*)d_out;                   // (B,T,N)
    float* outz = outx + (size_t)BB * TT * NN;     // (B,T,R)

    char* ws = (char*)d_ws;
    size_t off = 0;
    unsigned short* Jp = (unsigned short*)(ws + off); off += (size_t)BB * NN * NN * 2;
    unsigned short* V1 = (unsigned short*)(ws + off); off += (size_t)BB * TT * NN * 2;
    unsigned short* V2 = (unsigned short*)(ws + off); off += (size_t)BB * NN * TT * 2;
    float* x      = (float*)(ws + off); off += (size_t)BB * NN * 4;
    float* abuf   = (float*)(ws + off); off += (size_t)BB * TT * 4;
    float* part   = (float*)(ws + off); off += (size_t)BB * 64 * 4;
    float* part2  = (float*)(ws + off); off += (size_t)BB * 128 * 4;
    unsigned* cnt = (unsigned*)(ws + off); off += (size_t)BB * 32 * 4;
    unsigned* gen = (unsigned*)(ws + off); off += (size_t)BB * 32 * 4;
    // fallback-only buffers
    float* nm     = (float*)(ws + off); off += (size_t)BB * NN * RR * 4;
    float* rbuf   = (float*)(ws + off); off += (size_t)BB * NN * 4;
    float* Jrb    = (float*)(ws + off); off += (size_t)BB * NN * 4;
    float* zb     = (float*)(ws + off); off += (size_t)BB * RR * 4 + 256;
    float* part72 = (float*)(ws + off); off += (size_t)BB * 72 * 4;

    hipMemsetAsync(x,   0, (size_t)BB * NN * sizeof(float), stream);
    hipMemsetAsync(nm,  0, (size_t)BB * NN * RR * sizeof(float), stream);
    hipMemsetAsync(cnt, 0, (size_t)BB * 32 * sizeof(unsigned), stream);
    hipMemsetAsync(gen, 0, (size_t)BB * 32 * sizeof(unsigned), stream);

    k_convJ<<<BB * NN, 256, 0, stream>>>(J, Jp);

    void* kargs[] = {
        (void*)&Jp, (void*)&V1, (void*)&V2, (void*)&x,
        (void*)&abuf, (void*)&part, (void*)&part2, (void*)&cnt, (void*)&gen,
        (void*)&m, (void*)&wIn, (void*)&inputs, (void*)&f,
        (void*)&outx, (void*)&outz
    };
    hipError_t rc = hipLaunchCooperativeKernel((const void*)k_persist,
                                               dim3(GRID), dim3(256),
                                               kargs, 0, stream);
    if (rc != hipSuccess) {
        // fallback: proven round-3 path
        for (int t = 0; t < TT; ++t) {
            kA_fb<<<BB * (NBLK + VBLK), 256, 0, stream>>>(x, Jp, V1, nm, rbuf, abuf,
                                                          Jrb, zb, part72, t);
            kB_fb<<<BB * 8, 256, 0, stream>>>(V1, rbuf, abuf, Jrb, zb, part72,
                                              x, nm, m, wIn, inputs, f, outx, outz, t);
        }
    }
}